// Round 14
// baseline (123.322 us; speedup 1.0000x reference)
//
#include <hip/hip_runtime.h>

#define BI 128
#define BH 256
#define MT 32
#define NT 256

using f32x4  = __attribute__((ext_vector_type(4))) float;
using short8 = __attribute__((ext_vector_type(8))) short;

// ---------- bf16 helpers (RNE) ----------
__device__ __forceinline__ unsigned short f2bf(float f) {
  unsigned u = __float_as_uint(f);
  u = (u + 0x7FFFu + ((u >> 16) & 1u)) >> 16;
  return (unsigned short)u;
}
__device__ __forceinline__ float bf2f(unsigned short h) {
  return __uint_as_float(((unsigned)h) << 16);
}
__device__ __forceinline__ float fast_tanh(float v) {
  return 1.f - 2.f / (1.f + __expf(2.f * v));
}
__device__ __forceinline__ float fast_sigmoid(float v) {
  return 1.f / (1.f + __expf(-v));
}

// ---------- weight packing: W (HxK row-major f32) -> bf16 in B-fragment order ----------
__global__ void pack_w(const float* __restrict__ W, unsigned short* __restrict__ dst,
                       int K, int total) {
  int t = blockIdx.x * blockDim.x + threadIdx.x;
  if (t >= total) return;
  int lane = t & 63;
  int tile = t >> 6;
  int KT = K >> 5;
  int nf = tile / KT, kt = tile - nf * KT;
  int n  = nf * 16 + (lane & 15);
  int k0 = kt * 32 + (lane >> 4) * 8;
  const float* src = W + (size_t)n * K + k0;
#pragma unroll
  for (int j = 0; j < 8; ++j) dst[(size_t)t * 8 + j] = f2bf(src[j]);
}

// =============== Kernel E: ew = sigmoid([x,prev]@ev_w^T + b) -> out tail ===============
// Pure streaming: reads x+prev (67 MB), writes 0.26 MB. 8 threads per row.
__global__ __launch_bounds__(NT, 4) void ew_kernel(
    const float* __restrict__ x, const float* __restrict__ prev,
    const float* __restrict__ ev_w, const float* __restrict__ ev_b,
    float* __restrict__ out, int Bn) {
  const int tid = threadIdx.x;
  const int r0 = blockIdx.x * MT;
  int r = tid >> 3, p = tid & 7;
  float s = 0.f;
  const float* src = (p < 4) ? (x + (size_t)(r0 + r) * BI + p * 32)
                             : (prev + (size_t)(r0 + r) * BI + (p - 4) * 32);
  const float* wr = ev_w + p * 32;
#pragma unroll
  for (int i = 0; i < 8; ++i) {
    f32x4 a = *(const f32x4*)(src + i * 4);
    f32x4 w = *(const f32x4*)(wr + i * 4);
    s += a[0] * w[0] + a[1] * w[1] + a[2] * w[2] + a[3] * w[3];
  }
  s += __shfl_xor(s, 1);
  s += __shfl_xor(s, 2);
  s += __shfl_xor(s, 4);
  if (p == 0)
    out[(size_t)Bn * BH + r0 + r] = fast_sigmoid(s + ev_b[0]);
}

// =============== Kernel A: ha = sigmoid(hidden@attn^T + b) * hidden (PROVEN ~10us) ===============
// LDS: 0: h_bf [32][512B] swz (16384); 16384: ha_bf (16384) = 32768 B.
__global__ __launch_bounds__(NT, 3) void ha_kernel(
    const float* __restrict__ hidden, const float* __restrict__ attn_b,
    const unsigned short* __restrict__ attn_p,
    unsigned short* __restrict__ ha_out) {
  extern __shared__ char smem[];
  const int tid = threadIdx.x;
  const int lane = tid & 63;
  const int wid = tid >> 6;
  const int r0 = blockIdx.x * MT;
  const int lrow = lane & 15;
  const int lk = lane >> 4;

#pragma unroll
  for (int it = 0; it < 8; ++it) {
    int idx4 = it * NT + tid;
    int row = idx4 >> 6;
    int c = idx4 & 63;
    f32x4 v = *(const f32x4*)(hidden + (size_t)(r0 + row) * BH + c * 4);
    unsigned h01 = (unsigned)f2bf(v[0]) | ((unsigned)f2bf(v[1]) << 16);
    unsigned h23 = (unsigned)f2bf(v[2]) | ((unsigned)f2bf(v[3]) << 16);
    *(unsigned long long*)(smem + row * 512 + ((c * 8) ^ ((row & 7) << 4))) =
        (unsigned long long)h01 | ((unsigned long long)h23 << 32);
  }
  __syncthreads();

  f32x4 acc[2][4] = {};
  {
    const short8* bW = (const short8*)attn_p;
#pragma unroll
    for (int kt = 0; kt < 8; ++kt) {
      short8 ah[2];
#pragma unroll
      for (int mf = 0; mf < 2; ++mf) {
        int row = mf * 16 + lrow;
        ah[mf] = *(const short8*)(smem + row * 512 + ((kt * 64 + lk * 16) ^ ((row & 7) << 4)));
      }
#pragma unroll
      for (int nf = 0; nf < 4; ++nf) {
        short8 b = bW[((wid * 4 + nf) * 8 + kt) * 64 + lane];
#pragma unroll
        for (int mf = 0; mf < 2; ++mf)
          acc[mf][nf] = __builtin_amdgcn_mfma_f32_16x16x32_bf16(ah[mf], b, acc[mf][nf], 0, 0, 0);
      }
    }
  }

#pragma unroll
  for (int nf = 0; nf < 4; ++nf) {
    int col = wid * 64 + nf * 16 + lrow;
    float bb = attn_b[col];
#pragma unroll
    for (int mf = 0; mf < 2; ++mf) {
#pragma unroll
      for (int j = 0; j < 4; ++j) {
        int row = mf * 16 + lk * 4 + j;
        float aw = fast_sigmoid(acc[mf][nf][j] + bb);
        int hoff = row * 512 + ((col * 2) ^ ((row & 7) << 4));
        float h = bf2f(*(const unsigned short*)(smem + hoff));
        *(unsigned short*)(smem + 16384 + hoff) = f2bf(h * aw);
      }
    }
  }
  __syncthreads();

#pragma unroll
  for (int p = 0; p < 4; ++p) {
    int c = p * NT + tid;
    int row = c >> 5;
    int cp = (c & 31) * 16;
    f32x4 v = *(const f32x4*)(smem + 16384 + row * 512 + (cp ^ ((row & 7) << 4)));
    *(f32x4*)((char*)ha_out + (size_t)blockIdx.x * 16384 + (size_t)c * 16) = v;
  }
}

// =============== Kernel B: ic = tanh(x@W_in^T + b) -> packed bf16 in own out region ===============
// Pure ha-template. LDS: 0: x_bf [32][256B] swz (8192); 8192: ic_bf [32][512B] swz (16384) = 24576 B.
// Packed ic (16384 B/block) lands in the FIRST HALF of this block's own out span
// (bytes blk*32768 .. +16384) -> no cross-block overlap; rec_kernel reads then overwrites.
__global__ __launch_bounds__(NT, 3) void ic_kernel(
    const float* __restrict__ x, const float* __restrict__ w_in_b,
    const unsigned short* __restrict__ win_p,
    float* __restrict__ out) {
  extern __shared__ char smem[];
  const int tid = threadIdx.x;
  const int lane = tid & 63;
  const int wid = tid >> 6;
  const int r0 = blockIdx.x * MT;
  const int lrow = lane & 15;
  const int lk = lane >> 4;

  // stage x (32x128) -> bf16 swz LDS, coalesced
#pragma unroll
  for (int it = 0; it < 4; ++it) {
    int idx4 = it * NT + tid;
    int row = idx4 >> 5;
    int c = idx4 & 31;
    f32x4 v = *(const f32x4*)(x + (size_t)(r0 + row) * BI + c * 4);
    unsigned h01 = (unsigned)f2bf(v[0]) | ((unsigned)f2bf(v[1]) << 16);
    unsigned h23 = (unsigned)f2bf(v[2]) | ((unsigned)f2bf(v[3]) << 16);
    *(unsigned long long*)(smem + row * 256 + ((c * 8) ^ ((row & 7) << 4))) =
        (unsigned long long)h01 | ((unsigned long long)h23 << 32);
  }
  __syncthreads();

  // GEMM1: A from LDS
  f32x4 ic[2][4] = {};
  {
    const short8* bW = (const short8*)win_p;
#pragma unroll
    for (int kt = 0; kt < 4; ++kt) {
      short8 ax[2];
#pragma unroll
      for (int mf = 0; mf < 2; ++mf) {
        int row = mf * 16 + lrow;
        ax[mf] = *(const short8*)(smem + row * 256 + ((kt * 64 + lk * 16) ^ ((row & 7) << 4)));
      }
#pragma unroll
      for (int nf = 0; nf < 4; ++nf) {
        short8 b = bW[((wid * 4 + nf) * 4 + kt) * 64 + lane];
#pragma unroll
        for (int mf = 0; mf < 2; ++mf)
          ic[mf][nf] = __builtin_amdgcn_mfma_f32_16x16x32_bf16(ax[mf], b, ic[mf][nf], 0, 0, 0);
      }
    }
  }

  // tanh -> bf16 swz stash
#pragma unroll
  for (int nf = 0; nf < 4; ++nf) {
    int col = wid * 64 + nf * 16 + lrow;
    float bb = w_in_b[col];
#pragma unroll
    for (int mf = 0; mf < 2; ++mf) {
#pragma unroll
      for (int j = 0; j < 4; ++j) {
        int row = mf * 16 + lk * 4 + j;
        *(unsigned short*)(smem + 8192 + row * 512 + ((col * 2) ^ ((row & 7) << 4))) =
            f2bf(fast_tanh(ic[mf][nf][j] + bb));
      }
    }
  }
  __syncthreads();

  // coalesced 16 KB store into own out span (first half)
#pragma unroll
  for (int p = 0; p < 4; ++p) {
    int c = p * NT + tid;
    int row = c >> 5;
    int cp = (c & 31) * 16;
    f32x4 v = *(const f32x4*)(smem + 8192 + row * 512 + (cp ^ ((row & 7) << 4)));
    *(f32x4*)((char*)out + (size_t)blockIdx.x * 32768 + (size_t)c * 16) = v;
  }
}

// =============== Kernel C: rcc = ha@W_rec^T; out = h + dt/tau*(ic + tanh(rcc+b) - h)*(1+ew) ===============
// LDS: 0: ha_bf [32][512B] swz (16384); 16384: s f32 [32][1024B] swz (32768) = 49152 B.
// Packed ic read EARLY into registers (8 x u64); vmcnt(0) drained before the
// pre-epilogue barrier so no thread's out-write can precede any ic read.
__global__ __launch_bounds__(NT, 3) void rec_kernel(
    const float* __restrict__ hidden, const float* __restrict__ w_rec_b,
    const float* __restrict__ tau,
    const unsigned short* __restrict__ wrec_p,
    const unsigned short* __restrict__ ha_in,
    float* __restrict__ out, int Bn) {
  extern __shared__ char smem[];
  const int tid = threadIdx.x;
  const int lane = tid & 63;
  const int wid = tid >> 6;
  const int r0 = blockIdx.x * MT;
  const int lrow = lane & 15;
  const int lk = lane >> 4;

  // ---- T14: issue packed-ic loads first (consumed in epilogue) ----
  unsigned long long icp[8];
  {
    const char* icbase = (const char*)out + (size_t)blockIdx.x * 32768;
#pragma unroll
    for (int it = 0; it < 8; ++it)
      icp[it] = *(const unsigned long long*)(icbase + (it * 4 + wid) * 512 + lane * 8);
  }

  // stage ha (coalesced ws read -> swz LDS)
#pragma unroll
  for (int p = 0; p < 4; ++p) {
    int c = p * NT + tid;
    int row = c >> 5;
    int cp = (c & 31) * 16;
    f32x4 v = *(const f32x4*)((const char*)ha_in + (size_t)blockIdx.x * 16384 + (size_t)c * 16);
    *(f32x4*)(smem + row * 512 + (cp ^ ((row & 7) << 4))) = v;
  }
  __syncthreads();

  // GEMM3
  f32x4 rcc[2][4] = {};
  {
    const short8* bW = (const short8*)wrec_p;
#pragma unroll
    for (int kt = 0; kt < 8; ++kt) {
      short8 ah[2];
#pragma unroll
      for (int mf = 0; mf < 2; ++mf) {
        int row = mf * 16 + lrow;
        ah[mf] = *(const short8*)(smem + row * 512 + ((kt * 64 + lk * 16) ^ ((row & 7) << 4)));
      }
#pragma unroll
      for (int nf = 0; nf < 4; ++nf) {
        short8 b = bW[((wid * 4 + nf) * 8 + kt) * 64 + lane];
#pragma unroll
        for (int mf = 0; mf < 2; ++mf)
          rcc[mf][nf] = __builtin_amdgcn_mfma_f32_16x16x32_bf16(ah[mf], b, rcc[mf][nf], 0, 0, 0);
      }
    }
  }

  // s = tanh(rcc + b) -> f32 swz region
#pragma unroll
  for (int nf = 0; nf < 4; ++nf) {
    int col = wid * 64 + nf * 16 + lrow;
    float brec = w_rec_b[col];
#pragma unroll
    for (int mf = 0; mf < 2; ++mf) {
#pragma unroll
      for (int j = 0; j < 4; ++j) {
        int row = mf * 16 + lk * 4 + j;
        *(float*)(smem + 16384 + row * 1024 + ((col * 4) ^ ((row & 7) << 4))) =
            fast_tanh(rcc[mf][nf][j] + brec);
      }
    }
  }
  // drain ALL outstanding global loads (icp!) before any thread may write out
  asm volatile("s_waitcnt vmcnt(0)" ::: "memory");
  __syncthreads();

  // epilogue: out = h + dt/tau * (ic + s - h) * (1 + ew)
  {
    f32x4 t4 = *(const f32x4*)(tau + lane * 4);
    f32x4 dtt;
#pragma unroll
    for (int i = 0; i < 4; ++i) {
      float t = fminf(fmaxf(t4[i], 0.1f), 10.f);
      dtt[i] = 0.1f / t;
    }
#pragma unroll
    for (int it = 0; it < 8; ++it) {
      int row = it * 4 + wid;
      float e1 = 1.f + out[(size_t)Bn * BH + r0 + row];
      f32x4 s4 = *(const f32x4*)(smem + 16384 + row * 1024 + ((lane * 16) ^ ((row & 7) << 4)));
      f32x4 h4 = *(const f32x4*)(hidden + (size_t)(r0 + row) * BH + lane * 4);
      f32x4 o;
#pragma unroll
      for (int i = 0; i < 4; ++i) {
        float icv = bf2f((unsigned short)(icp[it] >> (16 * i)));
        o[i] = h4[i] + dtt[i] * (icv + s4[i] - h4[i]) * e1;
      }
      *(f32x4*)(out + (size_t)(r0 + row) * BH + lane * 4) = o;
    }
  }
}

extern "C" void kernel_launch(void* const* d_in, const int* in_sizes, int n_in,
                              void* d_out, int out_size, void* d_ws, size_t ws_size,
                              hipStream_t stream) {
  const float* x       = (const float*)d_in[0];
  const float* prev    = (const float*)d_in[1];
  const float* hidden  = (const float*)d_in[2];
  const float* W_in_w  = (const float*)d_in[3];
  const float* W_in_b  = (const float*)d_in[4];
  const float* W_rec_w = (const float*)d_in[5];
  const float* W_rec_b = (const float*)d_in[6];
  const float* attn_w  = (const float*)d_in[7];
  const float* attn_b  = (const float*)d_in[8];
  const float* ev_w    = (const float*)d_in[9];
  const float* ev_b    = (const float*)d_in[10];
  const float* tau     = (const float*)d_in[11];
  int Bn = in_sizes[0] / BI;

  unsigned short* ws = (unsigned short*)d_ws;
  unsigned short* win_p  = ws;             // 32768 elems
  unsigned short* attn_p = ws + 32768;     // 65536 elems
  unsigned short* wrec_p = ws + 98304;     // 65536 elems
  unsigned short* ha_ws  = ws + 163840;    // Bn*BH elems (33.5 MB)

  pack_w<<<(4096 + 255) / 256, 256, 0, stream>>>(W_in_w, win_p, BI, 4096);
  pack_w<<<(8192 + 255) / 256, 256, 0, stream>>>(attn_w, attn_p, BH, 8192);
  pack_w<<<(8192 + 255) / 256, 256, 0, stream>>>(W_rec_w, wrec_p, BH, 8192);

  ew_kernel<<<Bn / MT, NT, 0, stream>>>(x, prev, ev_w, ev_b, (float*)d_out, Bn);

  ha_kernel<<<Bn / MT, NT, 32768, stream>>>(hidden, attn_b, attn_p, ha_ws);

  ic_kernel<<<Bn / MT, NT, 24576, stream>>>(x, W_in_b, win_p, (float*)d_out);

  rec_kernel<<<Bn / MT, NT, 49152, stream>>>(
      hidden, W_rec_b, tau, wrec_p, ha_ws, (float*)d_out, Bn);
}

// Round 16
// 112.684 us; speedup vs baseline: 1.0944x; 1.0944x over previous
//
#include <hip/hip_runtime.h>

#define BI 128
#define BH 256
#define MT 32
#define NT 256

using f32x4  = __attribute__((ext_vector_type(4))) float;
using short8 = __attribute__((ext_vector_type(8))) short;

// ---------- bf16 helpers (RNE) ----------
__device__ __forceinline__ unsigned short f2bf(float f) {
  unsigned u = __float_as_uint(f);
  u = (u + 0x7FFFu + ((u >> 16) & 1u)) >> 16;
  return (unsigned short)u;
}
__device__ __forceinline__ float bf2f(unsigned short h) {
  return __uint_as_float(((unsigned)h) << 16);
}
__device__ __forceinline__ float fast_tanh(float v) {
  return 1.f - 2.f / (1.f + __expf(2.f * v));
}
__device__ __forceinline__ float fast_sigmoid(float v) {
  return 1.f / (1.f + __expf(-v));
}

// ---------- weight packing: W (HxK row-major f32) -> bf16 in B-fragment order ----------
__global__ void pack_w(const float* __restrict__ W, unsigned short* __restrict__ dst,
                       int K, int total) {
  int t = blockIdx.x * blockDim.x + threadIdx.x;
  if (t >= total) return;
  int lane = t & 63;
  int tile = t >> 6;
  int KT = K >> 5;
  int nf = tile / KT, kt = tile - nf * KT;
  int n  = nf * 16 + (lane & 15);
  int k0 = kt * 32 + (lane >> 4) * 8;
  const float* src = W + (size_t)n * K + k0;
#pragma unroll
  for (int j = 0; j < 8; ++j) dst[(size_t)t * 8 + j] = f2bf(src[j]);
}

// =============== Kernel A: ha = sigmoid(hidden@attn^T + b) * hidden (PROVEN ~8us) ===============
// LDS: 0: h_bf [32][512B] swz (16384); 16384: ha_bf (16384) = 32768 B.
__global__ __launch_bounds__(NT, 3) void ha_kernel(
    const float* __restrict__ hidden, const float* __restrict__ attn_b,
    const unsigned short* __restrict__ attn_p,
    unsigned short* __restrict__ ha_out) {
  extern __shared__ char smem[];
  const int tid = threadIdx.x;
  const int lane = tid & 63;
  const int wid = tid >> 6;
  const int r0 = blockIdx.x * MT;
  const int lrow = lane & 15;
  const int lk = lane >> 4;

#pragma unroll
  for (int it = 0; it < 8; ++it) {
    int idx4 = it * NT + tid;
    int row = idx4 >> 6;
    int c = idx4 & 63;
    f32x4 v = *(const f32x4*)(hidden + (size_t)(r0 + row) * BH + c * 4);
    unsigned h01 = (unsigned)f2bf(v[0]) | ((unsigned)f2bf(v[1]) << 16);
    unsigned h23 = (unsigned)f2bf(v[2]) | ((unsigned)f2bf(v[3]) << 16);
    *(unsigned long long*)(smem + row * 512 + ((c * 8) ^ ((row & 7) << 4))) =
        (unsigned long long)h01 | ((unsigned long long)h23 << 32);
  }
  __syncthreads();

  f32x4 acc[2][4] = {};
  {
    const short8* bW = (const short8*)attn_p;
#pragma unroll
    for (int kt = 0; kt < 8; ++kt) {
      short8 ah[2];
#pragma unroll
      for (int mf = 0; mf < 2; ++mf) {
        int row = mf * 16 + lrow;
        ah[mf] = *(const short8*)(smem + row * 512 + ((kt * 64 + lk * 16) ^ ((row & 7) << 4)));
      }
#pragma unroll
      for (int nf = 0; nf < 4; ++nf) {
        short8 b = bW[((wid * 4 + nf) * 8 + kt) * 64 + lane];
#pragma unroll
        for (int mf = 0; mf < 2; ++mf)
          acc[mf][nf] = __builtin_amdgcn_mfma_f32_16x16x32_bf16(ah[mf], b, acc[mf][nf], 0, 0, 0);
      }
    }
  }

#pragma unroll
  for (int nf = 0; nf < 4; ++nf) {
    int col = wid * 64 + nf * 16 + lrow;
    float bb = attn_b[col];
#pragma unroll
    for (int mf = 0; mf < 2; ++mf) {
#pragma unroll
      for (int j = 0; j < 4; ++j) {
        int row = mf * 16 + lk * 4 + j;
        float aw = fast_sigmoid(acc[mf][nf][j] + bb);
        int hoff = row * 512 + ((col * 2) ^ ((row & 7) << 4));
        float h = bf2f(*(const unsigned short*)(smem + hoff));
        *(unsigned short*)(smem + 16384 + hoff) = f2bf(h * aw);
      }
    }
  }
  __syncthreads();

#pragma unroll
  for (int p = 0; p < 4; ++p) {
    int c = p * NT + tid;
    int row = c >> 5;
    int cp = (c & 31) * 16;
    f32x4 v = *(const f32x4*)(smem + 16384 + row * 512 + (cp ^ ((row & 7) << 4)));
    *(f32x4*)((char*)ha_out + (size_t)blockIdx.x * 16384 + (size_t)c * 16) = v;
  }
}

// =============== Kernel B: ic = tanh(x@W_in^T+b) -> packed bf16; ew fused (lane-contiguous) ===============
// LDS: 0: x_bf [32][256B] swz (8192); 8192: ic_bf [32][512B] swz (16384); 24576: ews[32] f32.
// ew: while staging x, fuse dot(x_row, ev_w[0:128]) via 32-lane shuffle reduce; second
// lane-contiguous loop streams prev for dot(prev_row, ev_w[128:256]). Row<->(it,wave,half)
// is bijective per loop and the same lane writes/accumulates ews[row] -> race-free.
__global__ __launch_bounds__(NT, 3) void icew_kernel(
    const float* __restrict__ x, const float* __restrict__ prev,
    const float* __restrict__ w_in_b,
    const float* __restrict__ ev_w, const float* __restrict__ ev_b,
    const unsigned short* __restrict__ win_p,
    float* __restrict__ out, int Bn) {
  extern __shared__ char smem[];
  const int tid = threadIdx.x;
  const int lane = tid & 63;
  const int wid = tid >> 6;
  const int r0 = blockIdx.x * MT;
  const int lrow = lane & 15;
  const int lk = lane >> 4;

  // ---- stage x -> LDS bf16 swz, fused with ew x-part dot ----
#pragma unroll
  for (int it = 0; it < 4; ++it) {
    int idx4 = it * NT + tid;
    int row = idx4 >> 5;
    int c = idx4 & 31;
    f32x4 v = *(const f32x4*)(x + (size_t)(r0 + row) * BI + c * 4);
    f32x4 w = *(const f32x4*)(ev_w + c * 4);
    float p = v[0] * w[0] + v[1] * w[1] + v[2] * w[2] + v[3] * w[3];
    p += __shfl_xor(p, 1);
    p += __shfl_xor(p, 2);
    p += __shfl_xor(p, 4);
    p += __shfl_xor(p, 8);
    p += __shfl_xor(p, 16);
    if ((lane & 31) == 0) *(float*)(smem + 24576 + row * 4) = p;
    unsigned h01 = (unsigned)f2bf(v[0]) | ((unsigned)f2bf(v[1]) << 16);
    unsigned h23 = (unsigned)f2bf(v[2]) | ((unsigned)f2bf(v[3]) << 16);
    *(unsigned long long*)(smem + row * 256 + ((c * 8) ^ ((row & 7) << 4))) =
        (unsigned long long)h01 | ((unsigned long long)h23 << 32);
  }
  // ---- ew prev-part: lane-contiguous stream, dot only ----
#pragma unroll
  for (int it = 0; it < 4; ++it) {
    int idx4 = it * NT + tid;
    int row = idx4 >> 5;
    int c = idx4 & 31;
    f32x4 v = *(const f32x4*)(prev + (size_t)(r0 + row) * BI + c * 4);
    f32x4 w = *(const f32x4*)(ev_w + 128 + c * 4);
    float p = v[0] * w[0] + v[1] * w[1] + v[2] * w[2] + v[3] * w[3];
    p += __shfl_xor(p, 1);
    p += __shfl_xor(p, 2);
    p += __shfl_xor(p, 4);
    p += __shfl_xor(p, 8);
    p += __shfl_xor(p, 16);
    if ((lane & 31) == 0) {
      float* q = (float*)(smem + 24576 + row * 4);
      *q += p;  // same lane wrote x-part for this row -> in-order, race-free
    }
  }
  __syncthreads();

  // finalize ew -> out tail
  if (tid < MT)
    out[(size_t)Bn * BH + r0 + tid] =
        fast_sigmoid(*(const float*)(smem + 24576 + tid * 4) + ev_b[0]);

  // ---- GEMM1: A from LDS ----
  f32x4 ic[2][4] = {};
  {
    const short8* bW = (const short8*)win_p;
#pragma unroll
    for (int kt = 0; kt < 4; ++kt) {
      short8 ax[2];
#pragma unroll
      for (int mf = 0; mf < 2; ++mf) {
        int row = mf * 16 + lrow;
        ax[mf] = *(const short8*)(smem + row * 256 + ((kt * 64 + lk * 16) ^ ((row & 7) << 4)));
      }
#pragma unroll
      for (int nf = 0; nf < 4; ++nf) {
        short8 b = bW[((wid * 4 + nf) * 4 + kt) * 64 + lane];
#pragma unroll
        for (int mf = 0; mf < 2; ++mf)
          ic[mf][nf] = __builtin_amdgcn_mfma_f32_16x16x32_bf16(ax[mf], b, ic[mf][nf], 0, 0, 0);
      }
    }
  }

  // tanh -> bf16 swz stash
#pragma unroll
  for (int nf = 0; nf < 4; ++nf) {
    int col = wid * 64 + nf * 16 + lrow;
    float bb = w_in_b[col];
#pragma unroll
    for (int mf = 0; mf < 2; ++mf) {
#pragma unroll
      for (int j = 0; j < 4; ++j) {
        int row = mf * 16 + lk * 4 + j;
        *(unsigned short*)(smem + 8192 + row * 512 + ((col * 2) ^ ((row & 7) << 4))) =
            f2bf(fast_tanh(ic[mf][nf][j] + bb));
      }
    }
  }
  __syncthreads();

  // coalesced 16 KB store into own out span (first half)
#pragma unroll
  for (int p = 0; p < 4; ++p) {
    int c = p * NT + tid;
    int row = c >> 5;
    int cp = (c & 31) * 16;
    f32x4 v = *(const f32x4*)(smem + 8192 + row * 512 + (cp ^ ((row & 7) << 4)));
    *(f32x4*)((char*)out + (size_t)blockIdx.x * 32768 + (size_t)c * 16) = v;
  }
}

// =============== Kernel C: rcc = ha@W_rec^T; out = h + dt/tau*(ic + tanh(rcc+b) - h)*(1+ew) ===============
// LDS: 0: ha_bf [32][512B] swz (16384); 16384: s f32 [32][1024B] swz (32768) = 49152 B.
__global__ __launch_bounds__(NT, 3) void rec_kernel(
    const float* __restrict__ hidden, const float* __restrict__ w_rec_b,
    const float* __restrict__ tau,
    const unsigned short* __restrict__ wrec_p,
    const unsigned short* __restrict__ ha_in,
    float* __restrict__ out, int Bn) {
  extern __shared__ char smem[];
  const int tid = threadIdx.x;
  const int lane = tid & 63;
  const int wid = tid >> 6;
  const int r0 = blockIdx.x * MT;
  const int lrow = lane & 15;
  const int lk = lane >> 4;

  // T14: issue packed-ic loads first (consumed in epilogue)
  unsigned long long icp[8];
  {
    const char* icbase = (const char*)out + (size_t)blockIdx.x * 32768;
#pragma unroll
    for (int it = 0; it < 8; ++it)
      icp[it] = *(const unsigned long long*)(icbase + (it * 4 + wid) * 512 + lane * 8);
  }

  // stage ha
#pragma unroll
  for (int p = 0; p < 4; ++p) {
    int c = p * NT + tid;
    int row = c >> 5;
    int cp = (c & 31) * 16;
    f32x4 v = *(const f32x4*)((const char*)ha_in + (size_t)blockIdx.x * 16384 + (size_t)c * 16);
    *(f32x4*)(smem + row * 512 + (cp ^ ((row & 7) << 4))) = v;
  }
  __syncthreads();

  // GEMM3
  f32x4 rcc[2][4] = {};
  {
    const short8* bW = (const short8*)wrec_p;
#pragma unroll
    for (int kt = 0; kt < 8; ++kt) {
      short8 ah[2];
#pragma unroll
      for (int mf = 0; mf < 2; ++mf) {
        int row = mf * 16 + lrow;
        ah[mf] = *(const short8*)(smem + row * 512 + ((kt * 64 + lk * 16) ^ ((row & 7) << 4)));
      }
#pragma unroll
      for (int nf = 0; nf < 4; ++nf) {
        short8 b = bW[((wid * 4 + nf) * 8 + kt) * 64 + lane];
#pragma unroll
        for (int mf = 0; mf < 2; ++mf)
          rcc[mf][nf] = __builtin_amdgcn_mfma_f32_16x16x32_bf16(ah[mf], b, rcc[mf][nf], 0, 0, 0);
      }
    }
  }

  // s = tanh(rcc + b) -> f32 swz region
#pragma unroll
  for (int nf = 0; nf < 4; ++nf) {
    int col = wid * 64 + nf * 16 + lrow;
    float brec = w_rec_b[col];
#pragma unroll
    for (int mf = 0; mf < 2; ++mf) {
#pragma unroll
      for (int j = 0; j < 4; ++j) {
        int row = mf * 16 + lk * 4 + j;
        *(float*)(smem + 16384 + row * 1024 + ((col * 4) ^ ((row & 7) << 4))) =
            fast_tanh(rcc[mf][nf][j] + brec);
      }
    }
  }
  // drain ALL outstanding global loads (icp!) before any thread may write out
  asm volatile("s_waitcnt vmcnt(0)" ::: "memory");
  __syncthreads();

  // epilogue
  {
    f32x4 t4 = *(const f32x4*)(tau + lane * 4);
    f32x4 dtt;
#pragma unroll
    for (int i = 0; i < 4; ++i) {
      float t = fminf(fmaxf(t4[i], 0.1f), 10.f);
      dtt[i] = 0.1f / t;
    }
#pragma unroll
    for (int it = 0; it < 8; ++it) {
      int row = it * 4 + wid;
      float e1 = 1.f + out[(size_t)Bn * BH + r0 + row];
      f32x4 s4 = *(const f32x4*)(smem + 16384 + row * 1024 + ((lane * 16) ^ ((row & 7) << 4)));
      f32x4 h4 = *(const f32x4*)(hidden + (size_t)(r0 + row) * BH + lane * 4);
      f32x4 o;
#pragma unroll
      for (int i = 0; i < 4; ++i) {
        float icv = bf2f((unsigned short)(icp[it] >> (16 * i)));
        o[i] = h4[i] + dtt[i] * (icv + s4[i] - h4[i]) * e1;
      }
      *(f32x4*)(out + (size_t)(r0 + row) * BH + lane * 4) = o;
    }
  }
}

extern "C" void kernel_launch(void* const* d_in, const int* in_sizes, int n_in,
                              void* d_out, int out_size, void* d_ws, size_t ws_size,
                              hipStream_t stream) {
  const float* x       = (const float*)d_in[0];
  const float* prev    = (const float*)d_in[1];
  const float* hidden  = (const float*)d_in[2];
  const float* W_in_w  = (const float*)d_in[3];
  const float* W_in_b  = (const float*)d_in[4];
  const float* W_rec_w = (const float*)d_in[5];
  const float* W_rec_b = (const float*)d_in[6];
  const float* attn_w  = (const float*)d_in[7];
  const float* attn_b  = (const float*)d_in[8];
  const float* ev_w    = (const float*)d_in[9];
  const float* ev_b    = (const float*)d_in[10];
  const float* tau     = (const float*)d_in[11];
  int Bn = in_sizes[0] / BI;

  unsigned short* ws = (unsigned short*)d_ws;
  unsigned short* win_p  = ws;             // 32768 elems
  unsigned short* attn_p = ws + 32768;     // 65536 elems
  unsigned short* wrec_p = ws + 98304;     // 65536 elems
  unsigned short* ha_ws  = ws + 163840;    // Bn*BH elems (33.5 MB)

  pack_w<<<(4096 + 255) / 256, 256, 0, stream>>>(W_in_w, win_p, BI, 4096);
  pack_w<<<(8192 + 255) / 256, 256, 0, stream>>>(attn_w, attn_p, BH, 8192);
  pack_w<<<(8192 + 255) / 256, 256, 0, stream>>>(W_rec_w, wrec_p, BH, 8192);

  ha_kernel<<<Bn / MT, NT, 32768, stream>>>(hidden, attn_b, attn_p, ha_ws);

  icew_kernel<<<Bn / MT, NT, 24704, stream>>>(
      x, prev, W_in_b, ev_w, ev_b, win_p, (float*)d_out, Bn);

  rec_kernel<<<Bn / MT, NT, 49152, stream>>>(
      hidden, W_rec_b, tau, wrec_p, ha_ws, (float*)d_out, Bn);
}